// Round 7
// baseline (184.919 us; speedup 1.0000x reference)
//
#include <hip/hip_runtime.h>

#define HDIM 128

__device__ __forceinline__ ushort f2bf(float f) {
    unsigned x = __float_as_uint(f);
    unsigned r = (x + 0x7fffu + ((x >> 16) & 1u)) >> 16;   // RNE
    return (ushort)r;
}

// ---------- prep: zero deg + zero-rows of xs1/xs2 ----------
__global__ void prep_kernel(int* __restrict__ deg, int* __restrict__ xs1N,
                            int* __restrict__ xs2N, int N) {
    int i = blockIdx.x * blockDim.x + threadIdx.x;
    if (i < N) deg[i] = 0;
    if (i < 64) { xs1N[i] = 0; xs2N[i] = 0; }   // 128 ushorts = 64 ints each
}

__global__ void hist_kernel(const int* __restrict__ col, int* __restrict__ deg, int E) {
    int i = blockIdx.x * blockDim.x + threadIdx.x;
    if (i < E) atomicAdd(&deg[col[i]], 1);
}

// phase A: per-block (256-wide) exclusive scan of deg -> rowptr (partial), block sums
__global__ __launch_bounds__(256)
void scanA_kernel(const int* __restrict__ deg, int* __restrict__ rowptr,
                  int* __restrict__ blocksums, int N) {
    __shared__ int s[256];
    int t = threadIdx.x;
    int i = blockIdx.x * 256 + t;
    int v = (i < N) ? deg[i] : 0;
    s[t] = v;
    __syncthreads();
#pragma unroll
    for (int off = 1; off < 256; off <<= 1) {
        int u = (t >= off) ? s[t - off] : 0;
        __syncthreads();
        s[t] += u;
        __syncthreads();
    }
    if (i < N) rowptr[i] = s[t] - v;           // block-local exclusive
    if (t == 255) blocksums[blockIdx.x] = s[255];
}

// phase BC: every block re-scans the NB block sums locally, then applies offsets
__global__ __launch_bounds__(256)
void scanBC_kernel(const int* __restrict__ deg, const int* __restrict__ blocksums,
                   int* __restrict__ rowptr, int* __restrict__ cursor,
                   float* __restrict__ dinv, int N, int NB) {
    __shared__ int s[128];
    int t = threadIdx.x;
    if (t < 128) s[t] = (t < NB) ? blocksums[t] : 0;
    __syncthreads();
#pragma unroll
    for (int off = 1; off < 128; off <<= 1) {
        int u = (t >= off && t < 128) ? s[t - off] : 0;
        __syncthreads();
        if (t < 128) s[t] += u;
        __syncthreads();
    }
    int b = blockIdx.x;
    int off_b = (b == 0) ? 0 : s[b - 1];
    int i = b * 256 + t;
    if (i < N) {
        int p = rowptr[i] + off_b;
        rowptr[i] = p;
        cursor[i] = p;
        dinv[i]   = rsqrtf((float)(deg[i] + 1));   // +1 self loop
    }
    if (b == NB - 1 && t == 0) rowptr[N] = s[NB - 1];
}

__global__ void fill_kernel(const int* __restrict__ row, const int* __restrict__ col,
                            int* __restrict__ cursor, int* __restrict__ esrc, int E) {
    int i = blockIdx.x * blockDim.x + threadIdx.x;
    if (i < E) {
        int pos = atomicAdd(&cursor[col[i]], 1);
        esrc[pos] = row[i];
    }
}

// ---------- GEMM + row scale: xs[n,:] = bf16((X[n,:] @ W) * dinv[n]) ----------
template<int K, int NPB>
__global__ void gemm_scale_kernel(const float* __restrict__ X, const float* __restrict__ W,
                                  const float* __restrict__ dinv,
                                  ushort* __restrict__ xs, int N) {
    __shared__ float xr[NPB * K];
    int t  = threadIdx.x;            // 128 threads
    int n0 = blockIdx.x * NPB;
    for (int i = t; i < NPB * K; i += 128)
        xr[i] = X[(long)n0 * K + i];
    __syncthreads();

    float acc[NPB];
#pragma unroll
    for (int m = 0; m < NPB; ++m) acc[m] = 0.f;

    for (int k = 0; k < K; ++k) {
        float w = W[k * HDIM + t];
#pragma unroll
        for (int m = 0; m < NPB; ++m) acc[m] += xr[m * K + k] * w;
    }

#pragma unroll
    for (int m = 0; m < NPB; ++m) {
        int n = n0 + m;
        if (n < N) {
            float v = acc[m] * dinv[n];
            float w = __shfl_xor(v, 1);          // neighbor column's value
            if (!(t & 1)) {
                ushort2 u;
                u.x = f2bf(v);
                u.y = f2bf(w);
                ((ushort2*)xs)[(long)n * 64 + (t >> 1)] = u;
            }
        }
    }
}

// ---------- gather1 fused with gemm2 ----------
// per wave (node): agg over edges from xs1, h1 = relu(agg*dinv + b1),
// then xs2[node,:] = bf16( (h1 @ W2) * dinv[node] ) with W2 staged in LDS.
__global__ __launch_bounds__(1024)
void gather_gemm_kernel(const int* __restrict__ rowptr, const int* __restrict__ esrc,
                        const ushort* __restrict__ xs1, const float* __restrict__ dinv,
                        const float* __restrict__ b1, const float* __restrict__ W2,
                        ushort* __restrict__ xs2, int N) {
    __shared__ float w2s[HDIM * HDIM];   // 64 KB
    __shared__ float hs[16 * HDIM];      // 8 KB
    int tid = threadIdx.x;
    for (int i = tid; i < HDIM * HDIM; i += 1024)
        w2s[i] = W2[i];
    __syncthreads();

    int wave = tid >> 6;
    int lane = tid & 63;
    int node = blockIdx.x * 16 + wave;
    bool active = node < N;
    float di = 0.f;

    if (active) {
        const unsigned* rows = (const unsigned*)xs1;
        float ax = 0.f, ay = 0.f;

        int s = rowptr[node];
        int e = rowptr[node + 1];
        int total = e - s + 1;    // + self

        for (int base = 0; base < total; base += 64) {
            int p = base + lane;
            int idx = N;                              // zero row (pad)
            if (p == 0)           idx = node;         // self loop
            else if (p < total)   idx = esrc[s + p - 1];

            int m = total - base;
            if (m > 64) m = 64;
            for (int k = 0; k < m; k += 8) {
                int r[8];
#pragma unroll
                for (int i = 0; i < 8; ++i) r[i] = __shfl(idx, k + i);
                unsigned u[8];
#pragma unroll
                for (int i = 0; i < 8; ++i) u[i] = rows[((long)r[i] << 6) + lane];
#pragma unroll
                for (int i = 0; i < 8; ++i) {
                    ax += __uint_as_float(u[i] << 16);
                    ay += __uint_as_float(u[i] & 0xffff0000u);
                }
            }
        }

        di = dinv[node];
        int d0 = 2 * lane;
        float vx = ax * di + b1[d0];
        float vy = ay * di + b1[d0 + 1];
        vx = vx > 0.f ? vx : 0.f;
        vy = vy > 0.f ? vy : 0.f;
        ((float2*)(hs + wave * HDIM))[lane] = make_float2(vx, vy);
    }
    __syncthreads();

    if (active) {
        // matvec: lane owns output cols 2*lane, 2*lane+1
        float a0 = 0.f, a1 = 0.f;
        const float4* hp = (const float4*)(hs + wave * HDIM);
        const float2* wp = (const float2*)w2s;
        for (int k = 0; k < HDIM; k += 4) {
            float4 hk = hp[k >> 2];
            float2 w0 = wp[(k    ) * 64 + lane];
            float2 w1 = wp[(k + 1) * 64 + lane];
            float2 w2 = wp[(k + 2) * 64 + lane];
            float2 w3 = wp[(k + 3) * 64 + lane];
            a0 += hk.x * w0.x + hk.y * w1.x + hk.z * w2.x + hk.w * w3.x;
            a1 += hk.x * w0.y + hk.y * w1.y + hk.z * w2.y + hk.w * w3.y;
        }
        unsigned o = (unsigned)f2bf(a0 * di) | ((unsigned)f2bf(a1 * di) << 16);
        ((unsigned*)xs2)[(long)node * 64 + lane] = o;
    }
}

// ---------- gather2 fused with LN + Q heads (one wave per node) ----------
__global__ __launch_bounds__(256)
void gather_ln_kernel(const int* __restrict__ rowptr, const int* __restrict__ esrc,
                      const ushort* __restrict__ xs, const float* __restrict__ dinv,
                      const float* __restrict__ bvec, float* __restrict__ out,
                      const float* __restrict__ lng, const float* __restrict__ lnb,
                      const float* __restrict__ Wq1, const float* __restrict__ bq1,
                      const float* __restrict__ Wq2, const float* __restrict__ bq2,
                      float* __restrict__ q1, float* __restrict__ q2, int N) {
    __shared__ float w1s[HDIM * 5];
    __shared__ float w2s[HDIM * 5];
    for (int i = threadIdx.x; i < HDIM * 5; i += 256) {
        w1s[i] = Wq1[i];
        w2s[i] = Wq2[i];
    }
    __syncthreads();

    int wave = threadIdx.x >> 6;
    int lane = threadIdx.x & 63;
    int node = blockIdx.x * 4 + wave;
    if (node >= N) return;

    const unsigned* rows = (const unsigned*)xs;

    float ax = 0.f, ay = 0.f;

    int s = rowptr[node];
    int e = rowptr[node + 1];
    int total = e - s + 1;    // + self

    for (int base = 0; base < total; base += 64) {
        int p = base + lane;
        int idx = N;                              // zero row (pad)
        if (p == 0)           idx = node;         // self loop
        else if (p < total)   idx = esrc[s + p - 1];

        int m = total - base;
        if (m > 64) m = 64;
        for (int k = 0; k < m; k += 8) {
            int r[8];
#pragma unroll
            for (int i = 0; i < 8; ++i) r[i] = __shfl(idx, k + i);
            unsigned u[8];
#pragma unroll
            for (int i = 0; i < 8; ++i) u[i] = rows[((long)r[i] << 6) + lane];
#pragma unroll
            for (int i = 0; i < 8; ++i) {
                ax += __uint_as_float(u[i] << 16);
                ay += __uint_as_float(u[i] & 0xffff0000u);
            }
        }
    }

    float di = dinv[node];
    int d0 = 2 * lane;
    float vx = ax * di + bvec[d0];
    float vy = ay * di + bvec[d0 + 1];
    vx = vx > 0.f ? vx : 0.f;
    vy = vy > 0.f ? vy : 0.f;

    // ---- LayerNorm ----
    float sm = vx + vy, ss = vx * vx + vy * vy;
#pragma unroll
    for (int off = 32; off >= 1; off >>= 1) {
        sm += __shfl_xor(sm, off);
        ss += __shfl_xor(ss, off);
    }
    float mu  = sm * (1.0f / HDIM);
    float var = ss * (1.0f / HDIM) - mu * mu;
    float rs  = rsqrtf(var + 1e-5f);

    float h0 = (vx - mu) * rs * lng[d0]     + lnb[d0];
    float h1 = (vy - mu) * rs * lng[d0 + 1] + lnb[d0 + 1];
    ((float2*)(out + ((long)node << 7)))[lane] = make_float2(h0, h1);

    // ---- Q heads ----
    float p1[5], p2[5];
#pragma unroll
    for (int j = 0; j < 5; ++j) {
        p1[j] = h0 * w1s[d0 * 5 + j] + h1 * w1s[(d0 + 1) * 5 + j];
        p2[j] = h0 * w2s[d0 * 5 + j] + h1 * w2s[(d0 + 1) * 5 + j];
    }
#pragma unroll
    for (int off = 32; off >= 1; off >>= 1) {
#pragma unroll
        for (int j = 0; j < 5; ++j) {
            p1[j] += __shfl_xor(p1[j], off);
            p2[j] += __shfl_xor(p2[j], off);
        }
    }
    if (lane == 0) {
#pragma unroll
        for (int j = 0; j < 5; ++j) {
            q1[(long)node * 5 + j] = p1[j] + bq1[j];
            q2[(long)node * 5 + j] = p2[j] + bq2[j];
        }
    }
}

extern "C" void kernel_launch(void* const* d_in, const int* in_sizes, int n_in,
                              void* d_out, int out_size, void* d_ws, size_t ws_size,
                              hipStream_t stream) {
    const float* x    = (const float*)d_in[0];
    const int*   ei   = (const int*)d_in[1];
    const float* W1   = (const float*)d_in[2];
    const float* b1   = (const float*)d_in[3];
    const float* W2   = (const float*)d_in[4];
    const float* b2   = (const float*)d_in[5];
    const float* lng  = (const float*)d_in[6];
    const float* lnb  = (const float*)d_in[7];
    const float* Wq1  = (const float*)d_in[8];
    const float* bq1  = (const float*)d_in[9];
    const float* Wq2  = (const float*)d_in[10];
    const float* bq2  = (const float*)d_in[11];

    const int D = 64;
    const int N = in_sizes[0] / D;        // 32768
    const int E = in_sizes[1] / 2;        // 524288
    const int* row = ei;
    const int* col = ei + E;

    // workspace layout (xs1/xs2 each N+1 rows; row N is the zero row)
    ushort* xs1    = (ushort*)d_ws;                          // bf16  (N+1)*128
    ushort* xs2    = xs1 + (long)(N + 1) * HDIM;             // bf16  (N+1)*128
    float*  dinv   = (float*)(xs2 + (long)(N + 1) * HDIM);   // N f
    int*    deg    = (int*)(dinv + N);                       // N i
    int*    rowptr = deg + N;                                // N+1 i
    int*    cursor = rowptr + N + 1;                         // N i
    int*    esrc   = cursor + N;                             // E i
    int*    bsums  = esrc + E;                               // 128 i

    float* q1   = (float*)d_out;
    float* q2   = q1 + (long)N * 5;
    float* hout = q2 + (long)N * 5;

    const int NB = (N + 255) / 256;       // scan blocks (128)

    // ---- CSR build ----
    prep_kernel<<<NB, 256, 0, stream>>>(deg, (int*)(xs1 + (long)N * HDIM),
                                        (int*)(xs2 + (long)N * HDIM), N);
    hist_kernel<<<(E + 255) / 256, 256, 0, stream>>>(col, deg, E);
    scanA_kernel<<<NB, 256, 0, stream>>>(deg, rowptr, bsums, N);
    scanBC_kernel<<<NB, 256, 0, stream>>>(deg, bsums, rowptr, cursor, dinv, N, NB);
    fill_kernel<<<(E + 255) / 256, 256, 0, stream>>>(row, col, cursor, esrc, E);

    // ---- layer 1 GEMM: x @ W1 -> xs1 (bf16, pre-scaled) ----
    gemm_scale_kernel<64, 8><<<(N + 7) / 8, 128, 0, stream>>>(x, W1, dinv, xs1, N);

    // ---- gather1 + gemm2 fused: xs1 -> h1 -> xs2 (bf16, pre-scaled) ----
    gather_gemm_kernel<<<(N + 15) / 16, 1024, 0, stream>>>(
        rowptr, esrc, xs1, dinv, b1, W2, xs2, N);

    // ---- gather2 + LN + heads ----
    gather_ln_kernel<<<(N + 3) / 4, 256, 0, stream>>>(
        rowptr, esrc, xs2, dinv, b2, hout,
        lng, lnb, Wq1, bq1, Wq2, bq2, q1, q2, N);
}